// Round 5
// baseline (342.078 us; speedup 1.0000x reference)
//
#include <hip/hip_runtime.h>
#include <hip/hip_bf16.h>
#include <stdint.h>

typedef unsigned short ushort_t;
typedef __attribute__((ext_vector_type(8))) short short8;
typedef __attribute__((ext_vector_type(4))) float floatx4;

#define DEV __device__ __forceinline__

DEV ushort_t f2b(float f) {
  uint32_t x = __float_as_uint(f);
  uint32_t r = (x + 0x7FFFu + ((x >> 16) & 1u)) >> 16;
  return (ushort_t)r;
}
DEV float b2f(ushort_t u) { return __uint_as_float(((uint32_t)u) << 16); }

DEV void async16(const ushort_t* g, ushort_t* l) {
  __builtin_amdgcn_global_load_lds(
      (const __attribute__((address_space(1))) void*)g,
      (__attribute__((address_space(3))) void*)l, 16, 0, 0);
}

// ---------------- fused fp32 -> bf16 conversion (one launch) ----------------
struct Cvt7 {
  const float* src[7];
  ushort_t* dst[7];
  unsigned start[8];  // prefix, in float4 units
};
__global__ void cvt_all(Cvt7 a) {
  unsigned idx = blockIdx.x * blockDim.x + threadIdx.x;
  if (idx >= a.start[7]) return;
  int seg = 0;
#pragma unroll
  for (int j = 1; j < 7; j++) seg += (idx >= a.start[j]) ? 1 : 0;
  unsigned off = idx - a.start[seg];
  float4 v = ((const float4*)a.src[seg])[off];
  ((ushort4*)a.dst[seg])[off] = make_ushort4(f2b(v.x), f2b(v.y), f2b(v.z), f2b(v.w));
}

// ---------------- bf16 GEMM: C[M,N] = A[M,K] * B[N,K]^T ---------------------
// 128x128 tile, 256 thr (4 waves 2x2), wave 64x64 = 4x4 MFMA 16x16x32, BK=64.
// XOR swizzle (global-side of global_load_lds): 0 bank conflicts (R2/R4).
// DBUF=false: R4 2-barrier loop (for GEMMs with >=3 blocks/CU).
// DBUF=true:  single-barrier double-buffered pipeline, prefetch distance 1 —
//   for the 256-block GEMMs (1 block/CU: no partner waves, so the 2-barrier
//   loop fully exposes staging latency; dbuf hides it behind the MFMA body).
// MODE 0: outB = bf16(acc)                         (QKV)
// MODE 1: outB = bf16(2*acc); outF = 2*acc + bias  (mid; outF seeds d_out)
// MODE 2: outB = bf16(relu(acc + bias[n]))         (MLP hidden)
// MODE 3: outF[idx] += acc                         (final; unique owner, RMW)
template <int MODE, bool DBUF>
__launch_bounds__(256)
__global__ void gemm_bt(const ushort_t* __restrict__ A, const ushort_t* __restrict__ Bm,
                        int M, int N, int K,
                        ushort_t* __restrict__ outB, float* __restrict__ outF,
                        const float* __restrict__ bias) {
  __shared__ alignas(16) ushort_t As[(DBUF ? 2 : 1) * 128 * 64];
  __shared__ alignas(16) ushort_t Bs[(DBUF ? 2 : 1) * 128 * 64];
  const int tid = threadIdx.x;
  const int wave = tid >> 6, lane = tid & 63;
  const int wm = wave >> 1, wn = wave & 1;
  const int m0 = blockIdx.y * 128, n0 = blockIdx.x * 128;

  floatx4 acc[4][4];
#pragma unroll
  for (int i = 0; i < 4; i++)
#pragma unroll
    for (int j = 0; j < 4; j++) acc[i][j] = (floatx4){0.f, 0.f, 0.f, 0.f};

  // staging: call j covers rows wave*32 + j*8 + (lane>>3), global k-chunk
  // (lane&7) ^ ((lane>>3)&7). 16B/lane, 8 async16 per wave per stage.
  const int srow = wave * 32 + (lane >> 3);
  const int scol = (((lane & 7) ^ ((lane >> 3) & 7)) * 8);
  const ushort_t* gA = A + (size_t)(m0 + srow) * K + scol;
  const ushort_t* gB = Bm + (size_t)(n0 + srow) * K + scol;

  const int fr = lane & 15, fq = lane >> 4;
  const int sw = fr & 7;

  auto issueAB = [&](int buf) {
    ushort_t* lA = As + buf * 8192 + wave * 2048;
    ushort_t* lB = Bs + buf * 8192 + wave * 2048;
#pragma unroll
    for (int j = 0; j < 4; j++) {
      async16(gA + (size_t)j * 8 * K, lA + j * 512);
      async16(gB + (size_t)j * 8 * K, lB + j * 512);
    }
    gA += 64; gB += 64;
  };
  auto compute = [&](int buf) {
    const ushort_t* rA = As + buf * 8192 + (wm * 64 + fr) * 64;
    const ushort_t* rB = Bs + buf * 8192 + (wn * 64 + fr) * 64;
#pragma unroll
    for (int h = 0; h < 2; h++) {
      const int co = ((h * 4 + fq) ^ sw) * 8;
      short8 af[4], bfv[4];
#pragma unroll
      for (int mt = 0; mt < 4; mt++) af[mt] = *(const short8*)(rA + mt * 16 * 64 + co);
#pragma unroll
      for (int nt = 0; nt < 4; nt++) bfv[nt] = *(const short8*)(rB + nt * 16 * 64 + co);
#pragma unroll
      for (int mt = 0; mt < 4; mt++)
#pragma unroll
        for (int nt = 0; nt < 4; nt++)
          acc[mt][nt] = __builtin_amdgcn_mfma_f32_16x16x32_bf16(af[mt], bfv[nt], acc[mt][nt], 0, 0, 0);
    }
  };

  if constexpr (DBUF) {
    const int nk = K >> 6;  // even for all our K
    issueAB(0);
    for (int k = 0; k < nk; k += 2) {
      __syncthreads();       // drains buf0 loads (issued one body ago)
      issueAB(1);
      compute(0);
      __syncthreads();       // drains buf1 loads
      if (k + 2 < nk) issueAB(0);
      compute(1);
    }
  } else {
    for (int k0 = 0; k0 < K; k0 += 64) {
      issueAB(0);
      __syncthreads();
      compute(0);
      __syncthreads();
    }
  }

  const int crow = m0 + wm * 64 + (lane >> 4) * 4;
  const int ccol = n0 + wn * 64 + (lane & 15);
#pragma unroll
  for (int mt = 0; mt < 4; mt++)
#pragma unroll
    for (int nt = 0; nt < 4; nt++) {
      floatx4 a = acc[mt][nt];
#pragma unroll
      for (int r = 0; r < 4; r++) {
        const int gm = crow + mt * 16 + r;
        const int gn = ccol + nt * 16;
        const size_t idx = (size_t)gm * N + gn;
        float v = a[r];
        if constexpr (MODE == 0) {
          outB[idx] = f2b(v);
        } else if constexpr (MODE == 1) {
          float t = 2.f * v;
          outB[idx] = f2b(t);
          outF[idx] = t + bias[gn];
        } else if constexpr (MODE == 2) {
          float t = v + bias[gn];
          outB[idx] = f2b(t > 0.f ? t : 0.f);
        } else {
          outF[idx] += v;  // single owner per element; out pre-seeded by MODE1
        }
      }
    }
}

// ---------------- attention (degenerate mask -> diag + suffix sum) ----------
// z[q] = (e_q*v[q] + sum_{p>q} v[p]) / (e_q + (S-1-q)), e_q = exp(q.k/8)
__launch_bounds__(256)
__global__ void attn1(const ushort_t* __restrict__ qkv,
                      float* __restrict__ eG, float* __restrict__ psumG) {
  const int c = blockIdx.x & 31;
  const int i = (blockIdx.x >> 5) & 15;
  const int b = blockIdx.x >> 9;
  const int t = threadIdx.x, wave = t >> 6, h = t & 63;
  const size_t rowbase = (size_t)b * 2048 * 3072;
  float vacc = 0.f;
#pragma unroll 4
  for (int r = 0; r < 16; r++) {
    const int s = c * 64 + wave * 16 + r;
    const size_t rb = rowbase + (size_t)s * 3072 + i * 64 + h;
    float q = b2f(qkv[rb]);
    float k = b2f(qkv[rb + 1024]);
    float v = b2f(qkv[rb + 2048]);
    float d = q * k;
#pragma unroll
    for (int off = 32; off > 0; off >>= 1) d += __shfl_xor(d, off, 64);
    if (h == 0) eG[((size_t)(b * 16 + i)) * 2048 + s] = __expf(d * 0.125f);
    vacc += v;
  }
  __shared__ float vs[4][64];
  vs[wave][h] = vacc;
  __syncthreads();
  if (t < 64)
    psumG[(((size_t)(b * 16 + i)) * 32 + c) * 64 + t] =
        vs[0][t] + vs[1][t] + vs[2][t] + vs[3][t];
}

// Pass 2: 256 blocks x 256 thr; each wave owns one 64-s chunk. Loads batched
// 16-deep (independent of the serial `run` chain) for latency hiding.
__launch_bounds__(256)
__global__ void attn2(const ushort_t* __restrict__ qkv,
                      const float* __restrict__ eG, const float* __restrict__ psumG,
                      ushort_t* __restrict__ Z) {
  const int wave = threadIdx.x >> 6, h = threadIdx.x & 63;
  const int c = (blockIdx.x & 7) * 4 + wave;
  const int i = (blockIdx.x >> 3) & 15;
  const int b = blockIdx.x >> 7;
  const size_t rowbase = (size_t)b * 2048 * 3072;
  const size_t pbase = ((size_t)(b * 16 + i)) * 32;
  float run = 0.f;
#pragma unroll 8
  for (int cc = c + 1; cc < 32; cc++) run += psumG[(pbase + cc) * 64 + h];
  const size_t ebase = ((size_t)(b * 16 + i)) * 2048;
  for (int t4 = 3; t4 >= 0; t4--) {
    float vv[16], ee[16];
#pragma unroll
    for (int j = 0; j < 16; j++) {
      const int s = c * 64 + t4 * 16 + j;
      vv[j] = b2f(qkv[rowbase + (size_t)s * 3072 + 2048 + i * 64 + h]);
      ee[j] = eG[ebase + s];
    }
#pragma unroll
    for (int j = 15; j >= 0; j--) {
      const int s = c * 64 + t4 * 16 + j;
      float z = (ee[j] * vv[j] + run) / (ee[j] + (float)(2047 - s));
      Z[((size_t)b * 2048 + s) * 1024 + i * 64 + h] = f2b(z);
      run += vv[j];
    }
  }
}

// ---------------- launch ----------------------------------------------------
extern "C" void kernel_launch(void* const* d_in, const int* in_sizes, int n_in,
                              void* d_out, int out_size, void* d_ws, size_t ws_size,
                              hipStream_t stream) {
  const float* x     = (const float*)d_in[0];
  const float* W_Q   = (const float*)d_in[1];
  const float* W_K   = (const float*)d_in[2];
  const float* W_V   = (const float*)d_in[3];
  const float* W_O   = (const float*)d_in[4];
  const float* W_in  = (const float*)d_in[5];
  const float* b_in  = (const float*)d_in[6];
  const float* W_out = (const float*)d_in[7];
  const float* b_out = (const float*)d_in[8];
  float* out = (float*)d_out;

  char* base = (char*)d_ws;
  const size_t MB = 1048576;
  ushort_t* Xb    = (ushort_t*)(base + 0 * MB);    // 8 MB
  ushort_t* Wqkv  = (ushort_t*)(base + 8 * MB);    // 6 MB
  ushort_t* WOb   = (ushort_t*)(base + 14 * MB);   // 2 MB
  ushort_t* Z     = (ushort_t*)(base + 16 * MB);   // 8 MB
  ushort_t* QKV   = (ushort_t*)(base + 24 * MB);   // 24 MB
  ushort_t* midb  = (ushort_t*)(base + 48 * MB);   // 8 MB
  ushort_t* Winb  = (ushort_t*)(base + 56 * MB);   // 8 MB
  ushort_t* Woutb = (ushort_t*)(base + 64 * MB);   // 8 MB
  ushort_t* Hb    = (ushort_t*)(base + 72 * MB);   // 32 MB
  float*    eG    = (float*)(base + 104 * MB);           // 256 KB
  float*    psumG = (float*)(base + 104 * MB + 262144);  // 256 KB

  Cvt7 ca;
  ca.src[0] = x;     ca.dst[0] = Xb;
  ca.src[1] = W_Q;   ca.dst[1] = Wqkv;
  ca.src[2] = W_K;   ca.dst[2] = Wqkv + 1048576;
  ca.src[3] = W_V;   ca.dst[3] = Wqkv + 2097152;
  ca.src[4] = W_O;   ca.dst[4] = WOb;
  ca.src[5] = W_in;  ca.dst[5] = Winb;
  ca.src[6] = W_out; ca.dst[6] = Woutb;
  unsigned n4s[7] = {1048576, 262144, 262144, 262144, 262144, 1048576, 1048576};
  unsigned acc4 = 0;
  for (int j = 0; j < 7; j++) { ca.start[j] = acc4; acc4 += n4s[j]; }
  ca.start[7] = acc4;
  cvt_all<<<dim3((acc4 + 255) / 256), dim3(256), 0, stream>>>(ca);

  // QKV = X * Wqkv^T   [4096, 3072]   (768 blocks -> keep 2-barrier loop)
  gemm_bt<0, false><<<dim3(24, 32), 256, 0, stream>>>(Xb, Wqkv, 4096, 3072, 1024,
                                                      QKV, nullptr, nullptr);
  // attention -> Z [4096, 1024] bf16
  attn1<<<dim3(1024), 256, 0, stream>>>(QKV, eG, psumG);
  attn2<<<dim3(256), 256, 0, stream>>>(QKV, eG, psumG, Z);
  // mid = 2*(Z*W_O^T): midb = bf16(mid), out seeded with mid + b_out
  // (256 blocks = 1 block/CU -> double-buffered pipeline)
  gemm_bt<1, true><<<dim3(8, 32), 256, 0, stream>>>(Z, WOb, 4096, 1024, 1024,
                                                    midb, out, b_out);
  // H = relu(mid * W_in^T + b_in) [4096, 4096]  (1024 blocks -> 2-barrier)
  gemm_bt<2, false><<<dim3(32, 32), 256, 0, stream>>>(midb, Winb, 4096, 4096, 1024,
                                                      Hb, nullptr, b_in);
  // out += H * W_out^T  (256 blocks = 1 block/CU -> double-buffered pipeline)
  gemm_bt<3, true><<<dim3(8, 32), 256, 0, stream>>>(Hb, Woutb, 4096, 1024, 4096,
                                                    nullptr, out, b_out);
}

// Round 7
// 300.567 us; speedup vs baseline: 1.1381x; 1.1381x over previous
//
#include <hip/hip_runtime.h>
#include <hip/hip_bf16.h>
#include <stdint.h>

typedef unsigned short ushort_t;
typedef __attribute__((ext_vector_type(8))) short short8;
typedef __attribute__((ext_vector_type(4))) float floatx4;

#define DEV __device__ __forceinline__

DEV ushort_t f2b(float f) {
  uint32_t x = __float_as_uint(f);
  uint32_t r = (x + 0x7FFFu + ((x >> 16) & 1u)) >> 16;
  return (ushort_t)r;
}
DEV float b2f(ushort_t u) { return __uint_as_float(((uint32_t)u) << 16); }

DEV void async16(const ushort_t* g, ushort_t* l) {
  __builtin_amdgcn_global_load_lds(
      (const __attribute__((address_space(1))) void*)g,
      (__attribute__((address_space(3))) void*)l, 16, 0, 0);
}

// ---------------- fused fp32 -> bf16 conversion (one launch) ----------------
struct Cvt7 {
  const float* src[7];
  ushort_t* dst[7];
  unsigned start[8];  // prefix, in float4 units
};
__global__ void cvt_all(Cvt7 a) {
  unsigned idx = blockIdx.x * blockDim.x + threadIdx.x;
  if (idx >= a.start[7]) return;
  int seg = 0;
#pragma unroll
  for (int j = 1; j < 7; j++) seg += (idx >= a.start[j]) ? 1 : 0;
  unsigned off = idx - a.start[seg];
  float4 v = ((const float4*)a.src[seg])[off];
  ((ushort4*)a.dst[seg])[off] = make_ushort4(f2b(v.x), f2b(v.y), f2b(v.z), f2b(v.w));
}

// ---------------- bf16 GEMM: C[M,N] = A[M,K] * B[N,K]^T ---------------------
// Tile = (32*MT) x 128, 256 thr (4 waves 2x2), wave tile (16*MT) x 64 =
// MT x 4 MFMA 16x16x32 tiles. BK=64, 2-barrier K-loop (R5: dbuf REGRESSED —
// barrier vmcnt(0) drain defeats source-level prefetch; don't re-add).
// MT=4 (128x128) for GEMMs with >=3 blocks/CU; MT=2 (64x128) doubles the
// block count for the 256-block N=1024 GEMMs (1 -> 2 blocks/CU).
// STAGING LOOP BOUND IS MT (= TM/32): each async16 call covers 8 rows
// (64 lanes x 16B = 512 elem), each wave owns TM/4 rows. R6 had MT/4 -> only
// partial A staged -> absmax 24.6. Verified: MT=4 reproduces R4's staging.
// XOR swizzle on global side of global_load_lds: 0 bank conflicts (R2-R5).
// MODE 0: outB = bf16(acc)                         (QKV)
// MODE 1: outB = bf16(2*acc); outF = 2*acc + bias  (mid; outF seeds d_out)
// MODE 2: outB = bf16(relu(acc + bias[n]))         (MLP hidden)
// MODE 3: outF[idx] += acc                         (final; unique owner, RMW)
template <int MODE, int MT>
__launch_bounds__(256)
__global__ void gemm_bt(const ushort_t* __restrict__ A, const ushort_t* __restrict__ Bm,
                        int M, int N, int K,
                        ushort_t* __restrict__ outB, float* __restrict__ outF,
                        const float* __restrict__ bias) {
  constexpr int TM = 32 * MT;
  __shared__ alignas(16) ushort_t As[TM * 64];
  __shared__ alignas(16) ushort_t Bs[128 * 64];
  const int tid = threadIdx.x;
  const int wave = tid >> 6, lane = tid & 63;
  const int wm = wave >> 1, wn = wave & 1;
  const int m0 = blockIdx.y * TM, n0 = blockIdx.x * 128;

  floatx4 acc[MT][4];
#pragma unroll
  for (int i = 0; i < MT; i++)
#pragma unroll
    for (int j = 0; j < 4; j++) acc[i][j] = (floatx4){0.f, 0.f, 0.f, 0.f};

  // staging: 16B/lane; call j covers 8 rows; global k-chunk (lane&7)^((lane>>3)&7)
  const int r8 = lane >> 3;
  const int scol = (((lane & 7) ^ (r8 & 7)) * 8);
  const ushort_t* gA = A + (size_t)(m0 + wave * (TM / 4) + r8) * K + scol;
  const ushort_t* gB = Bm + (size_t)(n0 + wave * 32 + r8) * K + scol;
  ushort_t* lA = As + wave * (TM / 4) * 64;
  ushort_t* lB = Bs + wave * 2048;

  const int fr = lane & 15, fq = lane >> 4;
  const int sw = fr & 7;
  const ushort_t* rdA = As + (wm * 16 * MT + fr) * 64;
  const ushort_t* rdB = Bs + (wn * 64 + fr) * 64;

  for (int k0 = 0; k0 < K; k0 += 64) {
#pragma unroll
    for (int j = 0; j < MT; j++) async16(gA + (size_t)j * 8 * K, lA + j * 512);
#pragma unroll
    for (int j = 0; j < 4; j++) async16(gB + (size_t)j * 8 * K, lB + j * 512);
    gA += 64; gB += 64;
    __syncthreads();
#pragma unroll
    for (int h = 0; h < 2; h++) {
      const int co = ((h * 4 + fq) ^ sw) * 8;
      short8 af[MT], bfv[4];
#pragma unroll
      for (int mt = 0; mt < MT; mt++) af[mt] = *(const short8*)(rdA + mt * 16 * 64 + co);
#pragma unroll
      for (int nt = 0; nt < 4; nt++) bfv[nt] = *(const short8*)(rdB + nt * 16 * 64 + co);
#pragma unroll
      for (int mt = 0; mt < MT; mt++)
#pragma unroll
        for (int nt = 0; nt < 4; nt++)
          acc[mt][nt] = __builtin_amdgcn_mfma_f32_16x16x32_bf16(af[mt], bfv[nt], acc[mt][nt], 0, 0, 0);
    }
    __syncthreads();
  }

  const int crow = m0 + wm * 16 * MT + (lane >> 4) * 4;
  const int ccol = n0 + wn * 64 + (lane & 15);
#pragma unroll
  for (int mt = 0; mt < MT; mt++)
#pragma unroll
    for (int nt = 0; nt < 4; nt++) {
      floatx4 a = acc[mt][nt];
#pragma unroll
      for (int r = 0; r < 4; r++) {
        const int gm = crow + mt * 16 + r;
        const int gn = ccol + nt * 16;
        const size_t idx = (size_t)gm * N + gn;
        float v = a[r];
        if constexpr (MODE == 0) {
          outB[idx] = f2b(v);
        } else if constexpr (MODE == 1) {
          float t = 2.f * v;
          outB[idx] = f2b(t);
          outF[idx] = t + bias[gn];
        } else if constexpr (MODE == 2) {
          float t = v + bias[gn];
          outB[idx] = f2b(t > 0.f ? t : 0.f);
        } else {
          outF[idx] += v;  // single owner per element; out pre-seeded by MODE1
        }
      }
    }
}

// ---------------- attention (degenerate mask -> diag + suffix sum) ----------
// z[q] = (e_q*v[q] + sum_{p>q} v[p]) / (e_q + (S-1-q)), e_q = exp(q.k/8)
__launch_bounds__(256)
__global__ void attn1(const ushort_t* __restrict__ qkv,
                      float* __restrict__ eG, float* __restrict__ psumG) {
  const int c = blockIdx.x & 31;
  const int i = (blockIdx.x >> 5) & 15;
  const int b = blockIdx.x >> 9;
  const int t = threadIdx.x, wave = t >> 6, h = t & 63;
  const size_t rowbase = (size_t)b * 2048 * 3072;
  float vacc = 0.f;
#pragma unroll 4
  for (int r = 0; r < 16; r++) {
    const int s = c * 64 + wave * 16 + r;
    const size_t rb = rowbase + (size_t)s * 3072 + i * 64 + h;
    float q = b2f(qkv[rb]);
    float k = b2f(qkv[rb + 1024]);
    float v = b2f(qkv[rb + 2048]);
    float d = q * k;
#pragma unroll
    for (int off = 32; off > 0; off >>= 1) d += __shfl_xor(d, off, 64);
    if (h == 0) eG[((size_t)(b * 16 + i)) * 2048 + s] = __expf(d * 0.125f);
    vacc += v;
  }
  __shared__ float vs[4][64];
  vs[wave][h] = vacc;
  __syncthreads();
  if (t < 64)
    psumG[(((size_t)(b * 16 + i)) * 32 + c) * 64 + t] =
        vs[0][t] + vs[1][t] + vs[2][t] + vs[3][t];
}

// Pass 2: 256 blocks x 256 thr; each wave owns one 64-s chunk. Loads batched
// 16-deep (independent of the serial `run` chain) for latency hiding.
__launch_bounds__(256)
__global__ void attn2(const ushort_t* __restrict__ qkv,
                      const float* __restrict__ eG, const float* __restrict__ psumG,
                      ushort_t* __restrict__ Z) {
  const int wave = threadIdx.x >> 6, h = threadIdx.x & 63;
  const int c = (blockIdx.x & 7) * 4 + wave;
  const int i = (blockIdx.x >> 3) & 15;
  const int b = blockIdx.x >> 7;
  const size_t rowbase = (size_t)b * 2048 * 3072;
  const size_t pbase = ((size_t)(b * 16 + i)) * 32;
  float run = 0.f;
#pragma unroll 8
  for (int cc = c + 1; cc < 32; cc++) run += psumG[(pbase + cc) * 64 + h];
  const size_t ebase = ((size_t)(b * 16 + i)) * 2048;
  for (int t4 = 3; t4 >= 0; t4--) {
    float vv[16], ee[16];
#pragma unroll
    for (int j = 0; j < 16; j++) {
      const int s = c * 64 + t4 * 16 + j;
      vv[j] = b2f(qkv[rowbase + (size_t)s * 3072 + 2048 + i * 64 + h]);
      ee[j] = eG[ebase + s];
    }
#pragma unroll
    for (int j = 15; j >= 0; j--) {
      const int s = c * 64 + t4 * 16 + j;
      float z = (ee[j] * vv[j] + run) / (ee[j] + (float)(2047 - s));
      Z[((size_t)b * 2048 + s) * 1024 + i * 64 + h] = f2b(z);
      run += vv[j];
    }
  }
}

// ---------------- launch ----------------------------------------------------
extern "C" void kernel_launch(void* const* d_in, const int* in_sizes, int n_in,
                              void* d_out, int out_size, void* d_ws, size_t ws_size,
                              hipStream_t stream) {
  const float* x     = (const float*)d_in[0];
  const float* W_Q   = (const float*)d_in[1];
  const float* W_K   = (const float*)d_in[2];
  const float* W_V   = (const float*)d_in[3];
  const float* W_O   = (const float*)d_in[4];
  const float* W_in  = (const float*)d_in[5];
  const float* b_in  = (const float*)d_in[6];
  const float* W_out = (const float*)d_in[7];
  const float* b_out = (const float*)d_in[8];
  float* out = (float*)d_out;

  char* base = (char*)d_ws;
  const size_t MB = 1048576;
  ushort_t* Xb    = (ushort_t*)(base + 0 * MB);    // 8 MB
  ushort_t* Wqkv  = (ushort_t*)(base + 8 * MB);    // 6 MB
  ushort_t* WOb   = (ushort_t*)(base + 14 * MB);   // 2 MB
  ushort_t* Z     = (ushort_t*)(base + 16 * MB);   // 8 MB
  ushort_t* QKV   = (ushort_t*)(base + 24 * MB);   // 24 MB
  ushort_t* midb  = (ushort_t*)(base + 48 * MB);   // 8 MB
  ushort_t* Winb  = (ushort_t*)(base + 56 * MB);   // 8 MB
  ushort_t* Woutb = (ushort_t*)(base + 64 * MB);   // 8 MB
  ushort_t* Hb    = (ushort_t*)(base + 72 * MB);   // 32 MB
  float*    eG    = (float*)(base + 104 * MB);           // 256 KB
  float*    psumG = (float*)(base + 104 * MB + 262144);  // 256 KB

  Cvt7 ca;
  ca.src[0] = x;     ca.dst[0] = Xb;
  ca.src[1] = W_Q;   ca.dst[1] = Wqkv;
  ca.src[2] = W_K;   ca.dst[2] = Wqkv + 1048576;
  ca.src[3] = W_V;   ca.dst[3] = Wqkv + 2097152;
  ca.src[4] = W_O;   ca.dst[4] = WOb;
  ca.src[5] = W_in;  ca.dst[5] = Winb;
  ca.src[6] = W_out; ca.dst[6] = Woutb;
  unsigned n4s[7] = {1048576, 262144, 262144, 262144, 262144, 1048576, 1048576};
  unsigned acc4 = 0;
  for (int j = 0; j < 7; j++) { ca.start[j] = acc4; acc4 += n4s[j]; }
  ca.start[7] = acc4;
  cvt_all<<<dim3((acc4 + 255) / 256), dim3(256), 0, stream>>>(ca);

  // QKV = X * Wqkv^T   [4096, 3072]   (768 blocks, 3/CU, 128x128)
  gemm_bt<0, 4><<<dim3(24, 32), 256, 0, stream>>>(Xb, Wqkv, 4096, 3072, 1024,
                                                  QKV, nullptr, nullptr);
  // attention -> Z [4096, 1024] bf16
  attn1<<<dim3(1024), 256, 0, stream>>>(QKV, eG, psumG);
  attn2<<<dim3(256), 256, 0, stream>>>(QKV, eG, psumG, Z);
  // mid = 2*(Z*W_O^T): midb = bf16(mid), out seeded with mid + b_out
  // (64x128 tiles -> 512 blocks, 2/CU)
  gemm_bt<1, 2><<<dim3(8, 64), 256, 0, stream>>>(Z, WOb, 4096, 1024, 1024,
                                                 midb, out, b_out);
  // H = relu(mid * W_in^T + b_in) [4096, 4096]  (1024 blocks, 4/CU, 128x128)
  gemm_bt<2, 4><<<dim3(32, 32), 256, 0, stream>>>(midb, Winb, 4096, 4096, 1024,
                                                  Hb, nullptr, b_in);
  // out += H * W_out^T  (64x128 tiles -> 512 blocks, 2/CU)
  gemm_bt<3, 2><<<dim3(8, 64), 256, 0, stream>>>(Hb, Woutb, 4096, 1024, 4096,
                                                 nullptr, out, b_out);
}

// Round 8
// 292.241 us; speedup vs baseline: 1.1705x; 1.0285x over previous
//
#include <hip/hip_runtime.h>
#include <hip/hip_bf16.h>
#include <stdint.h>

typedef unsigned short ushort_t;
typedef __attribute__((ext_vector_type(8))) short short8;
typedef __attribute__((ext_vector_type(4))) float floatx4;

#define DEV __device__ __forceinline__

DEV ushort_t f2b(float f) {
  uint32_t x = __float_as_uint(f);
  uint32_t r = (x + 0x7FFFu + ((x >> 16) & 1u)) >> 16;
  return (ushort_t)r;
}
DEV float b2f(ushort_t u) { return __uint_as_float(((uint32_t)u) << 16); }

DEV void async16(const ushort_t* g, ushort_t* l) {
  __builtin_amdgcn_global_load_lds(
      (const __attribute__((address_space(1))) void*)g,
      (__attribute__((address_space(3))) void*)l, 16, 0, 0);
}

// ---------------- fused fp32 -> bf16 conversion (one launch) ----------------
struct Cvt7 {
  const float* src[7];
  ushort_t* dst[7];
  unsigned start[8];  // prefix, in float4 units
};
__global__ void cvt_all(Cvt7 a) {
  unsigned idx = blockIdx.x * blockDim.x + threadIdx.x;
  if (idx >= a.start[7]) return;
  int seg = 0;
#pragma unroll
  for (int j = 1; j < 7; j++) seg += (idx >= a.start[j]) ? 1 : 0;
  unsigned off = idx - a.start[seg];
  float4 v = ((const float4*)a.src[seg])[off];
  ((ushort4*)a.dst[seg])[off] = make_ushort4(f2b(v.x), f2b(v.y), f2b(v.z), f2b(v.w));
}

// ---------------- bf16 GEMM: C[M,N] = A[M,K=ldk] * B[N,ldk]^T ---------------
// Tile = (32*MT) x 128, 256 thr (4 waves 2x2), wave tile (16*MT) x 64.
// BK=64, 2-barrier K-loop (R5: dbuf regressed — barrier drains vmcnt anyway).
// Staging loop bound = MT (R6 bug: MT/4 staged only part of A -> absmax 24.6).
// XOR swizzle on global side of global_load_lds: 0 bank conflicts (R2-R7).
// SWZ: XCD y-colocation. HW flat id f = x + gx*y, XCD = f%8. Remap so all
//   x-blocks sharing one A row-block land on ONE XCD:
//   by = (f&7) + 8*(f/(8*gx)), bx = (f>>3)%gx  (bijection; requires gy%8==0).
//   R7 counters: MODE3 FETCH 143MB vs 40MB ideal = A refetched per-XCD.
// Kd: K-depth per block (= ldk unless split-K; then blockIdx.z selects slice).
// MODE 0: outB = bf16(acc)                         (QKV)
// MODE 1: outB = bf16(2*acc); outF = 2*acc + bias  (mid; outF seeds d_out)
// MODE 2: outB = bf16(relu(acc + bias[n]))         (MLP hidden)
// MODE 3: outF[z*M*N+idx] = acc                    (split-K partials)
template <int MODE, int MT, bool SWZ>
__launch_bounds__(256)
__global__ void gemm_bt(const ushort_t* __restrict__ A, const ushort_t* __restrict__ Bm,
                        int M, int N, int Kd, int ldk,
                        ushort_t* __restrict__ outB, float* __restrict__ outF,
                        const float* __restrict__ bias) {
  constexpr int TM = 32 * MT;
  __shared__ alignas(16) ushort_t As[TM * 64];
  __shared__ alignas(16) ushort_t Bs[128 * 64];
  const int tid = threadIdx.x;
  const int wave = tid >> 6, lane = tid & 63;
  const int wm = wave >> 1, wn = wave & 1;

  int bx, by;
  if constexpr (SWZ) {
    const int f = blockIdx.x + gridDim.x * blockIdx.y;
    by = (f & 7) + 8 * (f / (8 * gridDim.x));
    bx = (f >> 3) % gridDim.x;
  } else {
    bx = blockIdx.x; by = blockIdx.y;
  }
  const int m0 = by * TM, n0 = bx * 128;
  const int kz = blockIdx.z * Kd;

  floatx4 acc[MT][4];
#pragma unroll
  for (int i = 0; i < MT; i++)
#pragma unroll
    for (int j = 0; j < 4; j++) acc[i][j] = (floatx4){0.f, 0.f, 0.f, 0.f};

  // staging: 16B/lane; call j covers 8 rows; global k-chunk (lane&7)^((lane>>3)&7)
  const int r8 = lane >> 3;
  const int scol = (((lane & 7) ^ (r8 & 7)) * 8);
  const ushort_t* gA = A + (size_t)(m0 + wave * (TM / 4) + r8) * ldk + kz + scol;
  const ushort_t* gB = Bm + (size_t)(n0 + wave * 32 + r8) * ldk + kz + scol;
  ushort_t* lA = As + wave * (TM / 4) * 64;
  ushort_t* lB = Bs + wave * 2048;

  const int fr = lane & 15, fq = lane >> 4;
  const int sw = fr & 7;
  const ushort_t* rdA = As + (wm * 16 * MT + fr) * 64;
  const ushort_t* rdB = Bs + (wn * 64 + fr) * 64;

  for (int k0 = 0; k0 < Kd; k0 += 64) {
#pragma unroll
    for (int j = 0; j < MT; j++) async16(gA + (size_t)j * 8 * ldk, lA + j * 512);
#pragma unroll
    for (int j = 0; j < 4; j++) async16(gB + (size_t)j * 8 * ldk, lB + j * 512);
    gA += 64; gB += 64;
    __syncthreads();
#pragma unroll
    for (int h = 0; h < 2; h++) {
      const int co = ((h * 4 + fq) ^ sw) * 8;
      short8 af[MT], bfv[4];
#pragma unroll
      for (int mt = 0; mt < MT; mt++) af[mt] = *(const short8*)(rdA + mt * 16 * 64 + co);
#pragma unroll
      for (int nt = 0; nt < 4; nt++) bfv[nt] = *(const short8*)(rdB + nt * 16 * 64 + co);
#pragma unroll
      for (int mt = 0; mt < MT; mt++)
#pragma unroll
        for (int nt = 0; nt < 4; nt++)
          acc[mt][nt] = __builtin_amdgcn_mfma_f32_16x16x32_bf16(af[mt], bfv[nt], acc[mt][nt], 0, 0, 0);
    }
    __syncthreads();
  }

  const int crow = m0 + wm * 16 * MT + (lane >> 4) * 4;
  const int ccol = n0 + wn * 64 + (lane & 15);
  const size_t zoff = (size_t)blockIdx.z * M * N;
#pragma unroll
  for (int mt = 0; mt < MT; mt++)
#pragma unroll
    for (int nt = 0; nt < 4; nt++) {
      floatx4 a = acc[mt][nt];
#pragma unroll
      for (int r = 0; r < 4; r++) {
        const int gm = crow + mt * 16 + r;
        const int gn = ccol + nt * 16;
        const size_t idx = (size_t)gm * N + gn;
        float v = a[r];
        if constexpr (MODE == 0) {
          outB[idx] = f2b(v);
        } else if constexpr (MODE == 1) {
          float t = 2.f * v;
          outB[idx] = f2b(t);
          outF[idx] = t + bias[gn];
        } else if constexpr (MODE == 2) {
          float t = v + bias[gn];
          outB[idx] = f2b(t > 0.f ? t : 0.f);
        } else {
          outF[zoff + idx] = v;
        }
      }
    }
}

// ---------------- split-K=2 reduction: out += P0 + P1 -----------------------
__launch_bounds__(256)
__global__ void reduce2(const float4* __restrict__ P, float4* __restrict__ out, int n4) {
  int i = blockIdx.x * blockDim.x + threadIdx.x;
  int st = gridDim.x * blockDim.x;
  for (; i < n4; i += st) {
    float4 a = out[i];
    float4 p0 = P[i], p1 = P[i + 1048576];
    a.x += p0.x + p1.x;
    a.y += p0.y + p1.y;
    a.z += p0.z + p1.z;
    a.w += p0.w + p1.w;
    out[i] = a;
  }
}

// ---------------- attention (degenerate mask -> diag + suffix sum) ----------
// z[q] = (e_q*v[q] + sum_{p>q} v[p]) / (e_q + (S-1-q)), e_q = exp(q.k/8)
__launch_bounds__(256)
__global__ void attn1(const ushort_t* __restrict__ qkv,
                      float* __restrict__ eG, float* __restrict__ psumG) {
  const int c = blockIdx.x & 31;
  const int i = (blockIdx.x >> 5) & 15;
  const int b = blockIdx.x >> 9;
  const int t = threadIdx.x, wave = t >> 6, h = t & 63;
  const size_t rowbase = (size_t)b * 2048 * 3072;
  float vacc = 0.f;
#pragma unroll 4
  for (int r = 0; r < 16; r++) {
    const int s = c * 64 + wave * 16 + r;
    const size_t rb = rowbase + (size_t)s * 3072 + i * 64 + h;
    float q = b2f(qkv[rb]);
    float k = b2f(qkv[rb + 1024]);
    float v = b2f(qkv[rb + 2048]);
    float d = q * k;
#pragma unroll
    for (int off = 32; off > 0; off >>= 1) d += __shfl_xor(d, off, 64);
    if (h == 0) eG[((size_t)(b * 16 + i)) * 2048 + s] = __expf(d * 0.125f);
    vacc += v;
  }
  __shared__ float vs[4][64];
  vs[wave][h] = vacc;
  __syncthreads();
  if (t < 64)
    psumG[(((size_t)(b * 16 + i)) * 32 + c) * 64 + t] =
        vs[0][t] + vs[1][t] + vs[2][t] + vs[3][t];
}

// Pass 2: 256 blocks x 256 thr; each wave owns one 64-s chunk. Loads batched
// 16-deep (independent of the serial `run` chain) for latency hiding.
__launch_bounds__(256)
__global__ void attn2(const ushort_t* __restrict__ qkv,
                      const float* __restrict__ eG, const float* __restrict__ psumG,
                      ushort_t* __restrict__ Z) {
  const int wave = threadIdx.x >> 6, h = threadIdx.x & 63;
  const int c = (blockIdx.x & 7) * 4 + wave;
  const int i = (blockIdx.x >> 3) & 15;
  const int b = blockIdx.x >> 7;
  const size_t rowbase = (size_t)b * 2048 * 3072;
  const size_t pbase = ((size_t)(b * 16 + i)) * 32;
  float run = 0.f;
#pragma unroll 8
  for (int cc = c + 1; cc < 32; cc++) run += psumG[(pbase + cc) * 64 + h];
  const size_t ebase = ((size_t)(b * 16 + i)) * 2048;
  for (int t4 = 3; t4 >= 0; t4--) {
    float vv[16], ee[16];
#pragma unroll
    for (int j = 0; j < 16; j++) {
      const int s = c * 64 + t4 * 16 + j;
      vv[j] = b2f(qkv[rowbase + (size_t)s * 3072 + 2048 + i * 64 + h]);
      ee[j] = eG[ebase + s];
    }
#pragma unroll
    for (int j = 15; j >= 0; j--) {
      const int s = c * 64 + t4 * 16 + j;
      float z = (ee[j] * vv[j] + run) / (ee[j] + (float)(2047 - s));
      Z[((size_t)b * 2048 + s) * 1024 + i * 64 + h] = f2b(z);
      run += vv[j];
    }
  }
}

// ---------------- launch ----------------------------------------------------
extern "C" void kernel_launch(void* const* d_in, const int* in_sizes, int n_in,
                              void* d_out, int out_size, void* d_ws, size_t ws_size,
                              hipStream_t stream) {
  const float* x     = (const float*)d_in[0];
  const float* W_Q   = (const float*)d_in[1];
  const float* W_K   = (const float*)d_in[2];
  const float* W_V   = (const float*)d_in[3];
  const float* W_O   = (const float*)d_in[4];
  const float* W_in  = (const float*)d_in[5];
  const float* b_in  = (const float*)d_in[6];
  const float* W_out = (const float*)d_in[7];
  const float* b_out = (const float*)d_in[8];
  float* out = (float*)d_out;

  // ws layout. P (32 MB split-K partials) aliases [0,32): Xb/Wqkv/WOb/Z dead
  // by MODE3 (Z consumed by MODE1, QKV by attn2, midb/Winb by MODE2).
  char* base = (char*)d_ws;
  const size_t MB = 1048576;
  ushort_t* Xb    = (ushort_t*)(base + 0 * MB);    // 8 MB
  ushort_t* Wqkv  = (ushort_t*)(base + 8 * MB);    // 6 MB
  ushort_t* WOb   = (ushort_t*)(base + 14 * MB);   // 2 MB
  ushort_t* Z     = (ushort_t*)(base + 16 * MB);   // 8 MB
  ushort_t* QKV   = (ushort_t*)(base + 24 * MB);   // 24 MB
  ushort_t* midb  = (ushort_t*)(base + 48 * MB);   // 8 MB
  ushort_t* Winb  = (ushort_t*)(base + 56 * MB);   // 8 MB
  ushort_t* Woutb = (ushort_t*)(base + 64 * MB);   // 8 MB
  ushort_t* Hb    = (ushort_t*)(base + 72 * MB);   // 32 MB
  float*    P     = (float*)(base + 0 * MB);       // 32 MB [0,32) alias
  float*    eG    = (float*)(base + 104 * MB);           // 256 KB
  float*    psumG = (float*)(base + 104 * MB + 262144);  // 256 KB

  Cvt7 ca;
  ca.src[0] = x;     ca.dst[0] = Xb;
  ca.src[1] = W_Q;   ca.dst[1] = Wqkv;
  ca.src[2] = W_K;   ca.dst[2] = Wqkv + 1048576;
  ca.src[3] = W_V;   ca.dst[3] = Wqkv + 2097152;
  ca.src[4] = W_O;   ca.dst[4] = WOb;
  ca.src[5] = W_in;  ca.dst[5] = Winb;
  ca.src[6] = W_out; ca.dst[6] = Woutb;
  unsigned n4s[7] = {1048576, 262144, 262144, 262144, 262144, 1048576, 1048576};
  unsigned acc4 = 0;
  for (int j = 0; j < 7; j++) { ca.start[j] = acc4; acc4 += n4s[j]; }
  ca.start[7] = acc4;
  cvt_all<<<dim3((acc4 + 255) / 256), dim3(256), 0, stream>>>(ca);

  // QKV = X * Wqkv^T   [4096, 3072]   (768 blocks, 3/CU, 128x128, XCD swizzle)
  gemm_bt<0, 4, true><<<dim3(24, 32), 256, 0, stream>>>(Xb, Wqkv, 4096, 3072, 1024, 1024,
                                                        QKV, nullptr, nullptr);
  // attention -> Z [4096, 1024] bf16
  attn1<<<dim3(1024), 256, 0, stream>>>(QKV, eG, psumG);
  attn2<<<dim3(256), 256, 0, stream>>>(QKV, eG, psumG, Z);
  // mid = 2*(Z*W_O^T): midb = bf16(mid), out seeded with mid + b_out
  gemm_bt<1, 2, true><<<dim3(8, 64), 256, 0, stream>>>(Z, WOb, 4096, 1024, 1024, 1024,
                                                       midb, out, b_out);
  // H = relu(mid * W_in^T + b_in) [4096, 4096]  (1024 blocks, 4/CU; A/B traffic
  // symmetric at 8 MB each -> swizzle is a wash, keep natural mapping)
  gemm_bt<2, 4, false><<<dim3(32, 32), 256, 0, stream>>>(midb, Winb, 4096, 4096, 1024, 1024,
                                                         Hb, nullptr, b_in);
  // P[z] = H[:, z*2048:(z+1)*2048] * W_out^T slice  (1024 blocks, 4/CU)
  gemm_bt<3, 2, true><<<dim3(8, 64, 2), 256, 0, stream>>>(Hb, Woutb, 4096, 1024, 2048, 4096,
                                                          nullptr, P, nullptr);
  // out += P0 + P1
  reduce2<<<dim3(1024), 256, 0, stream>>>((const float4*)P, (float4*)out, 1048576);
}

// Round 9
// 290.119 us; speedup vs baseline: 1.1791x; 1.0073x over previous
//
#include <hip/hip_runtime.h>
#include <hip/hip_bf16.h>
#include <stdint.h>

typedef unsigned short ushort_t;
typedef __attribute__((ext_vector_type(8))) short short8;
typedef __attribute__((ext_vector_type(4))) float floatx4;

#define DEV __device__ __forceinline__

DEV ushort_t f2b(float f) {
  uint32_t x = __float_as_uint(f);
  uint32_t r = (x + 0x7FFFu + ((x >> 16) & 1u)) >> 16;
  return (ushort_t)r;
}
DEV float b2f(ushort_t u) { return __uint_as_float(((uint32_t)u) << 16); }

DEV void async16(const ushort_t* g, ushort_t* l) {
  __builtin_amdgcn_global_load_lds(
      (const __attribute__((address_space(1))) void*)g,
      (__attribute__((address_space(3))) void*)l, 16, 0, 0);
}

// ---------------- fused fp32 -> bf16 conversion (one launch) ----------------
struct Cvt7 {
  const float* src[7];
  ushort_t* dst[7];
  unsigned start[8];  // prefix, in float4 units
};
__global__ void cvt_all(Cvt7 a) {
  unsigned idx = blockIdx.x * blockDim.x + threadIdx.x;
  if (idx >= a.start[7]) return;
  int seg = 0;
#pragma unroll
  for (int j = 1; j < 7; j++) seg += (idx >= a.start[j]) ? 1 : 0;
  unsigned off = idx - a.start[seg];
  float4 v = ((const float4*)a.src[seg])[off];
  ((ushort4*)a.dst[seg])[off] = make_ushort4(f2b(v.x), f2b(v.y), f2b(v.z), f2b(v.w));
}

// ---------------- bf16 GEMM: C[M,N] = A[M,K=ldk] * B[N,ldk]^T ---------------
// Tile = (32*MT) x 128, 256 thr (4 waves 2x2), wave tile (16*MT) x 64.
// BK=64, 2-barrier K-loop (R5: dbuf regressed). Staging bound = MT (R6 bug).
// XOR LDS swizzle: 0 bank conflicts (R2-R8).
// XCD mapping (XCD = HW-flat-id % 8; gx*gy % 8 == 0 keeps z-slices aligned):
//  SWZ=0 natural: XCD = x%8 -> bx-colocation. Use when B slice-per-XCD fits L2
//        (B_bytes * (gx/8 rounded) <= ~2-3MB) and A can stream (refetch x8).
//  SWZ=1 y-coloc: all bx of one A row-group on one XCD; A fetched once.
//        Use when FULL B fits L2 (<= ~2-3MB). R8: MODE3 B=8MB thrashed -> L3.
//  SWZ=2 cluster2 (requires gx=8, gy=64): XCD owns 2 bx x 32 by ->
//        B/XCD = 2MB L2-resident + A refetch only x4. For MODE3.
// MODE 0: outB = bf16(acc)                         (QKV)
// MODE 1: outB = bf16(2*acc); outF = 2*acc + bias  (mid; outF seeds d_out)
// MODE 2: outB = bf16(relu(acc + bias[n]))         (MLP hidden)
// MODE 3: outF[z*M*N+idx] = acc                    (split-K partials)
template <int MODE, int MT, int SWZ>
__launch_bounds__(256)
__global__ void gemm_bt(const ushort_t* __restrict__ A, const ushort_t* __restrict__ Bm,
                        int M, int N, int Kd, int ldk,
                        ushort_t* __restrict__ outB, float* __restrict__ outF,
                        const float* __restrict__ bias) {
  constexpr int TM = 32 * MT;
  __shared__ alignas(16) ushort_t As[TM * 64];
  __shared__ alignas(16) ushort_t Bs[128 * 64];
  const int tid = threadIdx.x;
  const int wave = tid >> 6, lane = tid & 63;
  const int wm = wave >> 1, wn = wave & 1;

  int bx, by;
  if constexpr (SWZ == 1) {
    const int f = blockIdx.x + gridDim.x * blockIdx.y;
    by = (f & 7) + 8 * (f / (8 * gridDim.x));
    bx = (f >> 3) % gridDim.x;
  } else if constexpr (SWZ == 2) {
    const int x = blockIdx.x, y = blockIdx.y;  // gx=8: XCD = x
    bx = 2 * (x & 3) + (y & 1);
    by = (y >> 1) + 32 * (x >> 2);
  } else {
    bx = blockIdx.x; by = blockIdx.y;
  }
  const int m0 = by * TM, n0 = bx * 128;
  const int kz = blockIdx.z * Kd;

  floatx4 acc[MT][4];
#pragma unroll
  for (int i = 0; i < MT; i++)
#pragma unroll
    for (int j = 0; j < 4; j++) acc[i][j] = (floatx4){0.f, 0.f, 0.f, 0.f};

  // staging: 16B/lane; call j covers 8 rows; global k-chunk (lane&7)^((lane>>3)&7)
  const int r8 = lane >> 3;
  const int scol = (((lane & 7) ^ (r8 & 7)) * 8);
  const ushort_t* gA = A + (size_t)(m0 + wave * (TM / 4) + r8) * ldk + kz + scol;
  const ushort_t* gB = Bm + (size_t)(n0 + wave * 32 + r8) * ldk + kz + scol;
  ushort_t* lA = As + wave * (TM / 4) * 64;
  ushort_t* lB = Bs + wave * 2048;

  const int fr = lane & 15, fq = lane >> 4;
  const int sw = fr & 7;
  const ushort_t* rdA = As + (wm * 16 * MT + fr) * 64;
  const ushort_t* rdB = Bs + (wn * 64 + fr) * 64;

  for (int k0 = 0; k0 < Kd; k0 += 64) {
#pragma unroll
    for (int j = 0; j < MT; j++) async16(gA + (size_t)j * 8 * ldk, lA + j * 512);
#pragma unroll
    for (int j = 0; j < 4; j++) async16(gB + (size_t)j * 8 * ldk, lB + j * 512);
    gA += 64; gB += 64;
    __syncthreads();
#pragma unroll
    for (int h = 0; h < 2; h++) {
      const int co = ((h * 4 + fq) ^ sw) * 8;
      short8 af[MT], bfv[4];
#pragma unroll
      for (int mt = 0; mt < MT; mt++) af[mt] = *(const short8*)(rdA + mt * 16 * 64 + co);
#pragma unroll
      for (int nt = 0; nt < 4; nt++) bfv[nt] = *(const short8*)(rdB + nt * 16 * 64 + co);
#pragma unroll
      for (int mt = 0; mt < MT; mt++)
#pragma unroll
        for (int nt = 0; nt < 4; nt++)
          acc[mt][nt] = __builtin_amdgcn_mfma_f32_16x16x32_bf16(af[mt], bfv[nt], acc[mt][nt], 0, 0, 0);
    }
    __syncthreads();
  }

  const int crow = m0 + wm * 16 * MT + (lane >> 4) * 4;
  const int ccol = n0 + wn * 64 + (lane & 15);
  const size_t zoff = (size_t)blockIdx.z * M * N;
#pragma unroll
  for (int mt = 0; mt < MT; mt++)
#pragma unroll
    for (int nt = 0; nt < 4; nt++) {
      floatx4 a = acc[mt][nt];
#pragma unroll
      for (int r = 0; r < 4; r++) {
        const int gm = crow + mt * 16 + r;
        const int gn = ccol + nt * 16;
        const size_t idx = (size_t)gm * N + gn;
        float v = a[r];
        if constexpr (MODE == 0) {
          outB[idx] = f2b(v);
        } else if constexpr (MODE == 1) {
          float t = 2.f * v;
          outB[idx] = f2b(t);
          outF[idx] = t + bias[gn];
        } else if constexpr (MODE == 2) {
          float t = v + bias[gn];
          outB[idx] = f2b(t > 0.f ? t : 0.f);
        } else {
          outF[zoff + idx] = v;
        }
      }
    }
}

// ---------------- split-K=2 reduction: out += P0 + P1 -----------------------
__launch_bounds__(256)
__global__ void reduce2(const float4* __restrict__ P, float4* __restrict__ out, int n4) {
  int i = blockIdx.x * blockDim.x + threadIdx.x;
  int st = gridDim.x * blockDim.x;
  for (; i < n4; i += st) {
    float4 a = out[i];
    float4 p0 = P[i], p1 = P[i + 1048576];
    a.x += p0.x + p1.x;
    a.y += p0.y + p1.y;
    a.z += p0.z + p1.z;
    a.w += p0.w + p1.w;
    out[i] = a;
  }
}

// ---------------- attention (degenerate mask -> diag + suffix sum) ----------
// z[q] = (e_q*v[q] + sum_{p>q} v[p]) / (e_q + (S-1-q)), e_q = exp(q.k/8)
__launch_bounds__(256)
__global__ void attn1(const ushort_t* __restrict__ qkv,
                      float* __restrict__ eG, float* __restrict__ psumG) {
  const int c = blockIdx.x & 31;
  const int i = (blockIdx.x >> 5) & 15;
  const int b = blockIdx.x >> 9;
  const int t = threadIdx.x, wave = t >> 6, h = t & 63;
  const size_t rowbase = (size_t)b * 2048 * 3072;
  float vacc = 0.f;
#pragma unroll 4
  for (int r = 0; r < 16; r++) {
    const int s = c * 64 + wave * 16 + r;
    const size_t rb = rowbase + (size_t)s * 3072 + i * 64 + h;
    float q = b2f(qkv[rb]);
    float k = b2f(qkv[rb + 1024]);
    float v = b2f(qkv[rb + 2048]);
    float d = q * k;
#pragma unroll
    for (int off = 32; off > 0; off >>= 1) d += __shfl_xor(d, off, 64);
    if (h == 0) eG[((size_t)(b * 16 + i)) * 2048 + s] = __expf(d * 0.125f);
    vacc += v;
  }
  __shared__ float vs[4][64];
  vs[wave][h] = vacc;
  __syncthreads();
  if (t < 64)
    psumG[(((size_t)(b * 16 + i)) * 32 + c) * 64 + t] =
        vs[0][t] + vs[1][t] + vs[2][t] + vs[3][t];
}

// Pass 2: 256 blocks x 256 thr; each wave owns one 64-s chunk. Loads batched
// 16-deep (independent of the serial `run` chain) for latency hiding.
__launch_bounds__(256)
__global__ void attn2(const ushort_t* __restrict__ qkv,
                      const float* __restrict__ eG, const float* __restrict__ psumG,
                      ushort_t* __restrict__ Z) {
  const int wave = threadIdx.x >> 6, h = threadIdx.x & 63;
  const int c = (blockIdx.x & 7) * 4 + wave;
  const int i = (blockIdx.x >> 3) & 15;
  const int b = blockIdx.x >> 7;
  const size_t rowbase = (size_t)b * 2048 * 3072;
  const size_t pbase = ((size_t)(b * 16 + i)) * 32;
  float run = 0.f;
#pragma unroll 8
  for (int cc = c + 1; cc < 32; cc++) run += psumG[(pbase + cc) * 64 + h];
  const size_t ebase = ((size_t)(b * 16 + i)) * 2048;
  for (int t4 = 3; t4 >= 0; t4--) {
    float vv[16], ee[16];
#pragma unroll
    for (int j = 0; j < 16; j++) {
      const int s = c * 64 + t4 * 16 + j;
      vv[j] = b2f(qkv[rowbase + (size_t)s * 3072 + 2048 + i * 64 + h]);
      ee[j] = eG[ebase + s];
    }
#pragma unroll
    for (int j = 15; j >= 0; j--) {
      const int s = c * 64 + t4 * 16 + j;
      float z = (ee[j] * vv[j] + run) / (ee[j] + (float)(2047 - s));
      Z[((size_t)b * 2048 + s) * 1024 + i * 64 + h] = f2b(z);
      run += vv[j];
    }
  }
}

// ---------------- launch ----------------------------------------------------
extern "C" void kernel_launch(void* const* d_in, const int* in_sizes, int n_in,
                              void* d_out, int out_size, void* d_ws, size_t ws_size,
                              hipStream_t stream) {
  const float* x     = (const float*)d_in[0];
  const float* W_Q   = (const float*)d_in[1];
  const float* W_K   = (const float*)d_in[2];
  const float* W_V   = (const float*)d_in[3];
  const float* W_O   = (const float*)d_in[4];
  const float* W_in  = (const float*)d_in[5];
  const float* b_in  = (const float*)d_in[6];
  const float* W_out = (const float*)d_in[7];
  const float* b_out = (const float*)d_in[8];
  float* out = (float*)d_out;

  // ws layout. P (32 MB split-K partials) aliases [0,32): Xb/Wqkv/WOb/Z dead
  // by MODE3 (Z consumed by MODE1, QKV by attn2, midb/Winb by MODE2).
  char* base = (char*)d_ws;
  const size_t MB = 1048576;
  ushort_t* Xb    = (ushort_t*)(base + 0 * MB);    // 8 MB
  ushort_t* Wqkv  = (ushort_t*)(base + 8 * MB);    // 6 MB
  ushort_t* WOb   = (ushort_t*)(base + 14 * MB);   // 2 MB
  ushort_t* Z     = (ushort_t*)(base + 16 * MB);   // 8 MB
  ushort_t* QKV   = (ushort_t*)(base + 24 * MB);   // 24 MB
  ushort_t* midb  = (ushort_t*)(base + 48 * MB);   // 8 MB
  ushort_t* Winb  = (ushort_t*)(base + 56 * MB);   // 8 MB
  ushort_t* Woutb = (ushort_t*)(base + 64 * MB);   // 8 MB
  ushort_t* Hb    = (ushort_t*)(base + 72 * MB);   // 32 MB
  float*    P     = (float*)(base + 0 * MB);       // 32 MB [0,32) alias
  float*    eG    = (float*)(base + 104 * MB);           // 256 KB
  float*    psumG = (float*)(base + 104 * MB + 262144);  // 256 KB

  Cvt7 ca;
  ca.src[0] = x;     ca.dst[0] = Xb;
  ca.src[1] = W_Q;   ca.dst[1] = Wqkv;
  ca.src[2] = W_K;   ca.dst[2] = Wqkv + 1048576;
  ca.src[3] = W_V;   ca.dst[3] = Wqkv + 2097152;
  ca.src[4] = W_O;   ca.dst[4] = WOb;
  ca.src[5] = W_in;  ca.dst[5] = Winb;
  ca.src[6] = W_out; ca.dst[6] = Woutb;
  unsigned n4s[7] = {1048576, 262144, 262144, 262144, 262144, 1048576, 1048576};
  unsigned acc4 = 0;
  for (int j = 0; j < 7; j++) { ca.start[j] = acc4; acc4 += n4s[j]; }
  ca.start[7] = acc4;
  cvt_all<<<dim3((acc4 + 255) / 256), dim3(256), 0, stream>>>(ca);

  // QKV = X * Wqkv^T [4096,3072]. Natural: XCD = x%8 -> 3 B-slices (768 KB)
  // L2-resident per XCD; A streams. (R8 y-coloc put 6 MB of B per XCD.)
  gemm_bt<0, 4, 0><<<dim3(24, 32), 256, 0, stream>>>(Xb, Wqkv, 4096, 3072, 1024, 1024,
                                                     QKV, nullptr, nullptr);
  // attention -> Z [4096, 1024] bf16
  attn1<<<dim3(1024), 256, 0, stream>>>(QKV, eG, psumG);
  attn2<<<dim3(256), 256, 0, stream>>>(QKV, eG, psumG, Z);
  // mid = 2*(Z*W_O^T): y-coloc (full B = 2 MB fits L2; A fetched once)
  gemm_bt<1, 2, 1><<<dim3(8, 64), 256, 0, stream>>>(Z, WOb, 4096, 1024, 1024, 1024,
                                                    midb, out, b_out);
  // H = relu(mid*W_in^T + b_in) [4096,4096]. Natural: 4 B-slices = 1 MB/XCD.
  gemm_bt<2, 4, 0><<<dim3(32, 32), 256, 0, stream>>>(midb, Winb, 4096, 4096, 1024, 1024,
                                                     Hb, nullptr, b_in);
  // P[z] = H slice * W_out^T. cluster2: 2 bx x 32 by per XCD -> B 2MB L2-res.
  gemm_bt<3, 2, 2><<<dim3(8, 64, 2), 256, 0, stream>>>(Hb, Woutb, 4096, 1024, 2048, 4096,
                                                       nullptr, P, nullptr);
  // out += P0 + P1
  reduce2<<<dim3(1024), 256, 0, stream>>>((const float4*)P, (float4*)out, 1048576);
}